// Round 9
// baseline (4502.480 us; speedup 1.0000x reference)
//
#include <hip/hip_runtime.h>
#include <cstdint>
#include <cstddef>

// G=256 graphs, NP=1000 points, K=8 neighbors, H=8 heads, DH=10, D=80, NL=10 layers
// GEMMs via split-bf16 MFMA: x = hi + lo (bf16 each); C = Ahi*Bhi + Ahi*Blo + Alo*Bhi (~f32 accuracy).
// battn: 80-row tiles, one 16-row tile per wave -> per-wave-local LDS in all GEMM phases -> 2 barriers total.

typedef __attribute__((ext_vector_type(8))) short short8v;
typedef __attribute__((ext_vector_type(4))) float f32x4;

#define MFMA16(ACC, A, B) ACC = __builtin_amdgcn_mfma_f32_16x16x32_bf16(A, B, ACC, 0, 0, 0)
#define MF3(ACC, AH, AL, BH, BL) { MFMA16(ACC, AH, BH); MFMA16(ACC, AH, BL); MFMA16(ACC, AL, BH); }

__device__ __forceinline__ void splitbf(float x, unsigned short& hi, unsigned short& lo) {
  unsigned u = __float_as_uint(x);
  unsigned r = u + 0x7FFFu + ((u >> 16) & 1u);
  hi = (unsigned short)(r >> 16);
  float hf = __uint_as_float(((unsigned)hi) << 16);
  float lf = x - hf;
  unsigned u2 = __float_as_uint(lf);
  unsigned r2 = u2 + 0x7FFFu + ((u2 >> 16) & 1u);
  lo = (unsigned short)(r2 >> 16);
}

__device__ __forceinline__ float bf2f(unsigned short v) {
  return __uint_as_float(((unsigned)v) << 16);
}

// ---------------- KNN: unroll-4 float4 LDS reads, exact order + stable tie-break ----------------
__global__ __launch_bounds__(128) void knn_kernel(const float* __restrict__ hf, int* __restrict__ nbr) {
  __shared__ __align__(16) float cs[3000];
  int b = blockIdx.x;
  int g = b >> 3;
  int q = b & 7;  // 8 octants of 125 points
  for (int i = threadIdx.x; i < 3000; i += 128) {
    cs[i] = hf[((size_t)g * 1000 + (i / 3)) * 9 + (i % 3)];
  }
  __syncthreads();
  int tid = threadIdx.x;
  if (tid < 125) {
    int n = q * 125 + tid;
    float cx = cs[n * 3 + 0], cy = cs[n * 3 + 1], cz = cs[n * 3 + 2];
    float bd[8];
    int bi[8];
    #pragma unroll
    for (int q2 = 0; q2 < 8; ++q2) { bd[q2] = 3.402823466e38f; bi[q2] = 0; }
    for (int j = 0; j < 1000; j += 4) {
      float4 a = *reinterpret_cast<const float4*>(cs + j * 3);
      float4 b4 = *reinterpret_cast<const float4*>(cs + j * 3 + 4);
      float4 c4 = *reinterpret_cast<const float4*>(cs + j * 3 + 8);
      float d2v[4];
      {
        float dx = __fsub_rn(cx, a.x), dy = __fsub_rn(cy, a.y), dz = __fsub_rn(cz, a.z);
        d2v[0] = __fadd_rn(__fadd_rn(__fmul_rn(dx, dx), __fmul_rn(dy, dy)), __fmul_rn(dz, dz));
      }
      {
        float dx = __fsub_rn(cx, a.w), dy = __fsub_rn(cy, b4.x), dz = __fsub_rn(cz, b4.y);
        d2v[1] = __fadd_rn(__fadd_rn(__fmul_rn(dx, dx), __fmul_rn(dy, dy)), __fmul_rn(dz, dz));
      }
      {
        float dx = __fsub_rn(cx, b4.z), dy = __fsub_rn(cy, b4.w), dz = __fsub_rn(cz, c4.x);
        d2v[2] = __fadd_rn(__fadd_rn(__fmul_rn(dx, dx), __fmul_rn(dy, dy)), __fmul_rn(dz, dz));
      }
      {
        float dx = __fsub_rn(cx, c4.y), dy = __fsub_rn(cy, c4.z), dz = __fsub_rn(cz, c4.w);
        d2v[3] = __fadd_rn(__fadd_rn(__fmul_rn(dx, dx), __fmul_rn(dy, dy)), __fmul_rn(dz, dz));
      }
      #pragma unroll
      for (int u = 0; u < 4; ++u) {
        float d2 = d2v[u];
        if (d2 < bd[7]) {
          bd[7] = d2; bi[7] = j + u;
          #pragma unroll
          for (int q2 = 7; q2 >= 1; --q2) {
            if (bd[q2] < bd[q2 - 1]) {  // strict: lower index first on ties (top_k semantics)
              float tf = bd[q2]; bd[q2] = bd[q2 - 1]; bd[q2 - 1] = tf;
              int ti = bi[q2]; bi[q2] = bi[q2 - 1]; bi[q2 - 1] = ti;
            }
          }
        }
      }
    }
    #pragma unroll
    for (int kk = 0; kk < 8; ++kk) nbr[((size_t)g * 1000 + n) * 8 + kk] = bi[kk];
  }
}

// ---------------- BatchNorm stats (deterministic two-stage) ----------------
__global__ __launch_bounds__(256) void bn_stat1(const float* __restrict__ hf, float* __restrict__ partial) {
  __shared__ float red[4][18];
  int row = blockIdx.x * 256 + threadIdx.x;
  float s[9], ss[9];
  #pragma unroll
  for (int f = 0; f < 9; ++f) {
    float v = hf[(size_t)row * 9 + f];
    s[f] = v;
    ss[f] = v * v;
  }
  for (int off = 32; off > 0; off >>= 1) {
    #pragma unroll
    for (int f = 0; f < 9; ++f) {
      s[f] += __shfl_down(s[f], off);
      ss[f] += __shfl_down(ss[f], off);
    }
  }
  int wid = threadIdx.x >> 6, lane = threadIdx.x & 63;
  if (lane == 0) {
    #pragma unroll
    for (int f = 0; f < 9; ++f) { red[wid][f] = s[f]; red[wid][9 + f] = ss[f]; }
  }
  __syncthreads();
  if (threadIdx.x < 18) {
    partial[(size_t)blockIdx.x * 18 + threadIdx.x] =
        red[0][threadIdx.x] + red[1][threadIdx.x] + red[2][threadIdx.x] + red[3][threadIdx.x];
  }
}

__global__ __launch_bounds__(256) void bn_stat2(const float* __restrict__ partial, float* __restrict__ stats) {
  __shared__ double sd[9][28], qd[9][28];
  int tid = threadIdx.x;
  if (tid < 252) {
    int f = tid % 9, gq = tid / 9;
    double s = 0.0, q = 0.0;
    for (int b = gq; b < 1000; b += 28) {
      s += (double)partial[b * 18 + f];
      q += (double)partial[b * 18 + 9 + f];
    }
    sd[f][gq] = s;
    qd[f][gq] = q;
  }
  __syncthreads();
  if (tid < 9) {
    double s = 0.0, q = 0.0;
    for (int g2 = 0; g2 < 28; ++g2) { s += sd[tid][g2]; q += qd[tid][g2]; }
    double mu = s / 256000.0;
    double var = q / 256000.0 - mu * mu;
    stats[tid] = (float)mu;
    stats[9 + tid] = (float)(1.0 / sqrt(var + 1e-5));
  }
}

// ---------------- Weight split-transpose: W[R][C] -> BT_hi/lo[C][KS] bf16, k-pad zeroed ----------------
__global__ __launch_bounds__(256) void split_tr(const float* __restrict__ src, unsigned short* __restrict__ dhi,
                                                unsigned short* __restrict__ dlo, int R, int C, int KS) {
  const float* s = src + (size_t)blockIdx.x * R * C;
  unsigned short* dh = dhi + (size_t)blockIdx.x * C * KS;
  unsigned short* dl = dlo + (size_t)blockIdx.x * C * KS;
  int n = C * KS;
  for (int i = threadIdx.x; i < n; i += 256) {
    int c = i / KS, kk = i % KS;
    float v = (kk < R) ? s[kk * C + c] : 0.f;
    unsigned short h, l;
    splitbf(v, h, l);
    dh[i] = h;
    dl[i] = l;
  }
}

// ---------------- Embed: normalize + (9->80) ----------------
__global__ __launch_bounds__(320) void embed_kernel(const float* __restrict__ hf, const float* __restrict__ stats,
                                                    const float* __restrict__ gamma, const float* __restrict__ beta,
                                                    const float* __restrict__ We, const float* __restrict__ be,
                                                    float* __restrict__ h) {
  __shared__ __align__(16) float xs[40 * 9];
  size_t p0 = (size_t)blockIdx.x * 40;
  for (int i = threadIdx.x; i < 360; i += 320) {
    int f = i % 9;
    float x = hf[p0 * 9 + i];
    xs[i] = (x - stats[f]) * stats[9 + f] * gamma[f] + beta[f];
  }
  __syncthreads();
  int c = threadIdx.x % 80, pg = threadIdx.x / 80;
  float we[9];
  #pragma unroll
  for (int f = 0; f < 9; ++f) we[f] = We[f * 80 + c];
  float bias = be[c];
  for (int pp = 0; pp < 10; ++pp) {
    int p = pg * 10 + pp;
    float acc = 0.f;
    #pragma unroll
    for (int f = 0; f < 9; ++f) acc = fmaf(xs[p * 9 + f], we[f], acc);
    h[(p0 + p) * 80 + c] = acc + bias;
  }
}

// ---------------- K,V projection via split-bf16 MFMA (r7-proven) ----------------
__global__ __launch_bounds__(320) void kv_kernel(const float* __restrict__ h,
                                                 const unsigned short* __restrict__ WkH, const unsigned short* __restrict__ WkL,
                                                 const unsigned short* __restrict__ WvH, const unsigned short* __restrict__ WvL,
                                                 float* __restrict__ kb, float* __restrict__ vb) {
  __shared__ __align__(16) unsigned short ahi[48 * 104];
  __shared__ __align__(16) unsigned short alo[48 * 104];
  size_t p0 = (size_t)blockIdx.x * 40;
  int tid = threadIdx.x;
  int lane = tid & 63, wv = tid >> 6;
  int fr = lane & 15, fq = lane >> 4;
  for (int i = tid; i < 800; i += 320) {
    int row = i / 20, kq = i % 20;
    float4 v = reinterpret_cast<const float4*>(h + (p0 + row) * 80)[kq];
    unsigned short h0, l0, h1, l1, h2, l2, h3, l3;
    splitbf(v.x, h0, l0); splitbf(v.y, h1, l1); splitbf(v.z, h2, l2); splitbf(v.w, h3, l3);
    int off = row * 104 + kq * 4;
    *reinterpret_cast<unsigned*>(&ahi[off]) = (unsigned)h0 | ((unsigned)h1 << 16);
    *reinterpret_cast<unsigned*>(&ahi[off + 2]) = (unsigned)h2 | ((unsigned)h3 << 16);
    *reinterpret_cast<unsigned*>(&alo[off]) = (unsigned)l0 | ((unsigned)l1 << 16);
    *reinterpret_cast<unsigned*>(&alo[off + 2]) = (unsigned)l2 | ((unsigned)l3 << 16);
  }
  for (int i = tid; i < 384; i += 320) {
    int row = i >> 3, kk = 80 + ((i & 7) << 1);
    int off = row * 104 + kk;
    *reinterpret_cast<unsigned*>(&ahi[off]) = 0u;
    *reinterpret_cast<unsigned*>(&alo[off]) = 0u;
  }
  __syncthreads();
  int bcol = wv * 16 + fr;
  f32x4 ck0 = {0.f, 0.f, 0.f, 0.f}, ck1 = ck0, ck2 = ck0;
  f32x4 cv0 = ck0, cv1 = ck0, cv2 = ck0;
  #pragma unroll
  for (int ks = 0; ks < 3; ++ks) {
    int boff = bcol * 96 + ks * 32 + fq * 8;
    short8v bkh = *reinterpret_cast<const short8v*>(WkH + boff);
    short8v bkl = *reinterpret_cast<const short8v*>(WkL + boff);
    short8v bvh = *reinterpret_cast<const short8v*>(WvH + boff);
    short8v bvl = *reinterpret_cast<const short8v*>(WvL + boff);
    int a0 = (0 * 16 + fr) * 104 + ks * 32 + fq * 8;
    int a1 = (1 * 16 + fr) * 104 + ks * 32 + fq * 8;
    int a2 = (2 * 16 + fr) * 104 + ks * 32 + fq * 8;
    short8v ah0 = *reinterpret_cast<const short8v*>(ahi + a0);
    short8v al0 = *reinterpret_cast<const short8v*>(alo + a0);
    MF3(ck0, ah0, al0, bkh, bkl); MF3(cv0, ah0, al0, bvh, bvl);
    short8v ah1 = *reinterpret_cast<const short8v*>(ahi + a1);
    short8v al1 = *reinterpret_cast<const short8v*>(alo + a1);
    MF3(ck1, ah1, al1, bkh, bkl); MF3(cv1, ah1, al1, bvh, bvl);
    short8v ah2 = *reinterpret_cast<const short8v*>(ahi + a2);
    short8v al2 = *reinterpret_cast<const short8v*>(alo + a2);
    MF3(ck2, ah2, al2, bkh, bkl); MF3(cv2, ah2, al2, bvh, bvl);
  }
  #pragma unroll
  for (int j = 0; j < 4; ++j) {
    int r0 = fq * 4 + j;
    kb[(p0 + r0) * 80 + bcol] = ck0[j];
    vb[(p0 + r0) * 80 + bcol] = cv0[j];
    int r1 = 16 + r0;
    kb[(p0 + r1) * 80 + bcol] = ck1[j];
    vb[(p0 + r1) * 80 + bcol] = cv1[j];
    int r2 = 32 + r0;
    if (r2 < 40) {
      kb[(p0 + r2) * 80 + bcol] = ck2[j];
      vb[(p0 + r2) * 80 + bcol] = cv2[j];
    }
  }
}

// ---------------- Attention for one point (f32 exact, split-write result) ----------------
__device__ __forceinline__ void attn_point(int p, int hh, const int* __restrict__ nb, size_t gbase,
                                           const float* __restrict__ kb, const float* __restrict__ vb,
                                           unsigned short* __restrict__ ahi, unsigned short* __restrict__ alo) {
  float qv[10];
  #pragma unroll
  for (int d2 = 0; d2 < 5; ++d2) {
    int off = p * 168 + hh * 10 + 2 * d2;
    unsigned uh = *reinterpret_cast<const unsigned*>(&ahi[off]);
    unsigned ul = *reinterpret_cast<const unsigned*>(&alo[off]);
    qv[2 * d2] = bf2f((unsigned short)uh) + bf2f((unsigned short)ul);
    qv[2 * d2 + 1] = bf2f((unsigned short)(uh >> 16)) + bf2f((unsigned short)(ul >> 16));
  }
  float sv[8];
  float denom = 0.f;
  #pragma unroll
  for (int kk = 0; kk < 8; ++kk) {
    const float2* kr = reinterpret_cast<const float2*>(kb + (gbase + nb[kk]) * 80 + hh * 10);
    float acc = 0.f;
    #pragma unroll
    for (int d2 = 0; d2 < 5; ++d2) {
      float2 kv2 = kr[d2];
      acc = fmaf(qv[2 * d2], kv2.x, acc);
      acc = fmaf(qv[2 * d2 + 1], kv2.y, acc);
    }
    float s = acc * 0.31622776601683794f;
    s = fminf(fmaxf(s, -5.f), 5.f);
    s = expf(s);
    sv[kk] = s;
    denom += s;
  }
  float wV[10] = {0, 0, 0, 0, 0, 0, 0, 0, 0, 0};
  #pragma unroll
  for (int kk = 0; kk < 8; ++kk) {
    const float2* vr = reinterpret_cast<const float2*>(vb + (gbase + nb[kk]) * 80 + hh * 10);
    #pragma unroll
    for (int d2 = 0; d2 < 5; ++d2) {
      float2 vv = vr[d2];
      wV[2 * d2] = fmaf(sv[kk], vv.x, wV[2 * d2]);
      wV[2 * d2 + 1] = fmaf(sv[kk], vv.y, wV[2 * d2 + 1]);
    }
  }
  float dn = denom + 1e-6f;
  #pragma unroll
  for (int d2 = 0; d2 < 5; ++d2) {
    float x0 = wV[2 * d2] / dn;
    float x1 = wV[2 * d2 + 1] / dn;
    unsigned short h0, l0, h1, l1;
    splitbf(x0, h0, l0); splitbf(x1, h1, l1);
    int off = p * 168 + hh * 10 + 2 * d2;
    *reinterpret_cast<unsigned*>(&ahi[off]) = (unsigned)h0 | ((unsigned)h1 << 16);
    *reinterpret_cast<unsigned*>(&alo[off]) = (unsigned)l0 | ((unsigned)l1 << 16);
  }
}

// ---------------- Fused layer: 80-row tile, 16 rows/wave, 2 barriers ----------------
__global__ __launch_bounds__(320) void battn_kernel(const float* __restrict__ h, const float* __restrict__ kb,
                                                    const float* __restrict__ vb, const int* __restrict__ nbr,
                                                    const unsigned short* __restrict__ WqH, const unsigned short* __restrict__ WqL,
                                                    const unsigned short* __restrict__ WoH, const unsigned short* __restrict__ WoL,
                                                    const float* __restrict__ bo,
                                                    const unsigned short* __restrict__ W1H, const unsigned short* __restrict__ W1L,
                                                    const float* __restrict__ b1,
                                                    const unsigned short* __restrict__ W2H, const unsigned short* __restrict__ W2L,
                                                    const float* __restrict__ b2, float* __restrict__ hout) {
  __shared__ __align__(16) unsigned short ahi[80 * 168];  // split buffer: h -> q -> attn -> h2 -> ts (per-wave rows)
  __shared__ __align__(16) unsigned short alo[80 * 168];
  int b = blockIdx.x;
  int xcd = b & 7;
  int r = b >> 3;               // 0..415
  int graph = (xcd << 5) + (r / 13);
  int t = r % 13;               // 13 tiles/graph: 12 x 80 rows + 1 x 40 rows
  size_t gbase = (size_t)graph * 1000;
  size_t pbase = gbase + (size_t)t * 80;
  int nrows = (t == 12) ? 40 : 80;
  int tid = threadIdx.x;
  int lane = tid & 63, wv = tid >> 6;
  int fr = lane & 15, fq = lane >> 4;
  int rowbase = wv * 16;
  // nbr prefetch for attention (p1 always valid: p1 < 40 <= nrows)
  int p1 = tid >> 3, hh = tid & 7;
  int p2 = p1 + 40;
  bool has2 = p2 < nrows;
  int nb1[8], nb2[8];
  #pragma unroll
  for (int kk = 0; kk < 8; ++kk) nb1[kk] = nbr[(pbase + p1) * 8 + kk];
  if (has2) {
    #pragma unroll
    for (int kk = 0; kk < 8; ++kk) nb2[kk] = nbr[(pbase + p2) * 8 + kk];
  }
  // ---- stage own 16 rows: h split (cols 0..79) + zero pad (cols 80..95); no barrier needed after ----
  #pragma unroll
  for (int s = 0; s < 5; ++s) {
    int i = lane + 64 * s;            // 0..319 covers 16 rows x 20 float4
    int rl = i / 20, kq = i % 20;
    int row = rowbase + rl;
    float4 v = {0.f, 0.f, 0.f, 0.f};
    if (row < nrows) v = reinterpret_cast<const float4*>(h + (pbase + row) * 80)[kq];
    unsigned short h0, l0, h1, l1, h2_, l2, h3, l3;
    splitbf(v.x, h0, l0); splitbf(v.y, h1, l1); splitbf(v.z, h2_, l2); splitbf(v.w, h3, l3);
    int off = row * 168 + kq * 4;
    *reinterpret_cast<unsigned*>(&ahi[off]) = (unsigned)h0 | ((unsigned)h1 << 16);
    *reinterpret_cast<unsigned*>(&ahi[off + 2]) = (unsigned)h2_ | ((unsigned)h3 << 16);
    *reinterpret_cast<unsigned*>(&alo[off]) = (unsigned)l0 | ((unsigned)l1 << 16);
    *reinterpret_cast<unsigned*>(&alo[off + 2]) = (unsigned)l2 | ((unsigned)l3 << 16);
  }
  #pragma unroll
  for (int s = 0; s < 2; ++s) {
    int i = lane + 64 * s;            // 0..127 covers 16 rows x 8 u32 (16 pad cols)
    int row = rowbase + (i >> 3);
    int kk = 80 + ((i & 7) << 1);
    int off = row * 168 + kk;
    *reinterpret_cast<unsigned*>(&ahi[off]) = 0u;
    *reinterpret_cast<unsigned*>(&alo[off]) = 0u;
  }
  // ---- q = h @ Wq: own rows only (A rows = rowbase+fr, C rows = rowbase+fq*4+j) ----
  {
    f32x4 C[5] = {};
    #pragma unroll
    for (int ks = 0; ks < 3; ++ks) {
      int aoff = (rowbase + fr) * 168 + ks * 32 + fq * 8;
      short8v ah = *reinterpret_cast<const short8v*>(ahi + aoff);
      short8v al = *reinterpret_cast<const short8v*>(alo + aoff);
      #pragma unroll
      for (int ct = 0; ct < 5; ++ct) {
        int boff = (ct * 16 + fr) * 96 + ks * 32 + fq * 8;
        short8v bh = *reinterpret_cast<const short8v*>(WqH + boff);
        short8v bl = *reinterpret_cast<const short8v*>(WqL + boff);
        MF3(C[ct], ah, al, bh, bl);
      }
    }
    // write q split over dead h split (own rows, cols 0..79)
    #pragma unroll
    for (int ct = 0; ct < 5; ++ct) {
      int col = ct * 16 + fr;
      #pragma unroll
      for (int j = 0; j < 4; ++j) {
        int row = rowbase + fq * 4 + j;
        unsigned short hh_, ll_;
        splitbf(C[ct][j], hh_, ll_);
        ahi[row * 168 + col] = hh_;
        alo[row * 168 + col] = ll_;
      }
    }
  }
  __syncthreads();  // B1: all q rows visible for attention
  // ---- attention: 2 points per thread; writes attn split over q (cross-wave rows) ----
  attn_point(p1, hh, nb1, gbase, kb, vb, ahi, alo);
  if (has2) attn_point(p2, hh, nb2, gbase, kb, vb, ahi, alo);
  __syncthreads();  // B2: attn visible; everything after is wave-local
  // ---- Wo MFMA + h2 epilogue (own rows) ----
  f32x4 O[5] = {};
  {
    #pragma unroll
    for (int ks = 0; ks < 3; ++ks) {
      int aoff = (rowbase + fr) * 168 + ks * 32 + fq * 8;
      short8v ah = *reinterpret_cast<const short8v*>(ahi + aoff);
      short8v al = *reinterpret_cast<const short8v*>(alo + aoff);
      #pragma unroll
      for (int ct = 0; ct < 5; ++ct) {
        int boff = (ct * 16 + fr) * 96 + ks * 32 + fq * 8;
        short8v bh = *reinterpret_cast<const short8v*>(WoH + boff);
        short8v bl = *reinterpret_cast<const short8v*>(WoL + boff);
        MF3(O[ct], ah, al, bh, bl);
      }
    }
    #pragma unroll
    for (int ct = 0; ct < 5; ++ct) {
      int col = ct * 16 + fr;
      float bias = bo[col];
      #pragma unroll
      for (int j = 0; j < 4; ++j) {
        int row = rowbase + fq * 4 + j;
        float hv = (row < nrows) ? h[(pbase + row) * 80 + col] : 0.f;
        O[ct][j] = hv + O[ct][j] + bias;
        unsigned short hh_, ll_;
        splitbf(O[ct][j], hh_, ll_);
        ahi[row * 168 + col] = hh_;
        alo[row * 168 + col] = ll_;
      }
    }
  }
  // ---- W1 MFMA + ts epilogue (own rows; ts cols 0..159 overwrite h2+pad after reads) ----
  {
    f32x4 T[10] = {};
    #pragma unroll
    for (int ks = 0; ks < 3; ++ks) {
      int aoff = (rowbase + fr) * 168 + ks * 32 + fq * 8;
      short8v ah = *reinterpret_cast<const short8v*>(ahi + aoff);
      short8v al = *reinterpret_cast<const short8v*>(alo + aoff);
      #pragma unroll
      for (int ct = 0; ct < 10; ++ct) {
        int boff = (ct * 16 + fr) * 96 + ks * 32 + fq * 8;
        short8v bh = *reinterpret_cast<const short8v*>(W1H + boff);
        short8v bl = *reinterpret_cast<const short8v*>(W1L + boff);
        MF3(T[ct], ah, al, bh, bl);
      }
    }
    #pragma unroll
    for (int ct = 0; ct < 10; ++ct) {
      int col = ct * 16 + fr;
      float bias = b1[col];
      #pragma unroll
      for (int j = 0; j < 4; ++j) {
        int row = rowbase + fq * 4 + j;
        float tv = fmaxf(T[ct][j] + bias, 0.f);
        unsigned short hh_, ll_;
        splitbf(tv, hh_, ll_);
        ahi[row * 168 + col] = hh_;
        alo[row * 168 + col] = ll_;
      }
    }
  }
  // ---- W2 MFMA (K=160, reads own ts rows) + hout = h2(regs) + ts@W2 + b2 ----
  {
    f32x4 D[5] = {};
    #pragma unroll
    for (int ks = 0; ks < 5; ++ks) {
      int aoff = (rowbase + fr) * 168 + ks * 32 + fq * 8;
      short8v ah = *reinterpret_cast<const short8v*>(ahi + aoff);
      short8v al = *reinterpret_cast<const short8v*>(alo + aoff);
      #pragma unroll
      for (int ct = 0; ct < 5; ++ct) {
        int boff = (ct * 16 + fr) * 160 + ks * 32 + fq * 8;
        short8v bh = *reinterpret_cast<const short8v*>(W2H + boff);
        short8v bl = *reinterpret_cast<const short8v*>(W2L + boff);
        MF3(D[ct], ah, al, bh, bl);
      }
    }
    #pragma unroll
    for (int ct = 0; ct < 5; ++ct) {
      int col = ct * 16 + fr;
      float bias = b2[col];
      #pragma unroll
      for (int j = 0; j < 4; ++j) {
        int row = rowbase + fq * 4 + j;
        if (row < nrows) hout[(pbase + row) * 80 + col] = O[ct][j] + D[ct][j] + bias;
      }
    }
  }
}

// ---------------- Readout MLP 80->40->20->64->{3,1} (f32 vector) ----------------
__global__ __launch_bounds__(320) void readout_kernel(const float* __restrict__ h, const float* __restrict__ Wr0,
                                                      const float* __restrict__ br0, const float* __restrict__ Wr1,
                                                      const float* __restrict__ br1, const float* __restrict__ Wr2,
                                                      const float* __restrict__ br2, const float* __restrict__ Wc,
                                                      const float* __restrict__ Wb, const float* __restrict__ bb,
                                                      float* __restrict__ out) {
  __shared__ __align__(16) float hs[3200];
  __shared__ __align__(16) float y0s[40 * 40];
  __shared__ __align__(16) float y1s[40 * 20];
  __shared__ __align__(16) float y2s[40 * 64];
  size_t p0 = (size_t)blockIdx.x * 40;
  int tid = threadIdx.x;
  {
    const float4* src = reinterpret_cast<const float4*>(h + p0 * 80);
    float4* dst = reinterpret_cast<float4*>(hs);
    for (int i = tid; i < 800; i += 320) dst[i] = src[i];
  }
  __syncthreads();
  {  // y0 = relu(h@Wr0 + br0)
    int c = tid % 40, grp = tid / 40;  // 0..7
    if (grp < 5) {
      float wcol[80];
      #pragma unroll
      for (int kk = 0; kk < 80; ++kk) wcol[kk] = Wr0[kk * 40 + c];
      float bias = br0[c];
      float acc[8] = {};
      #pragma unroll
      for (int j = 0; j < 8; ++j) {
        const float4* r4 = reinterpret_cast<const float4*>(hs + (grp * 8 + j) * 80);
        #pragma unroll
        for (int kq = 0; kq < 20; ++kq) {
          float4 hv = r4[kq];
          acc[j] = fmaf(hv.x, wcol[4 * kq + 0], acc[j]);
          acc[j] = fmaf(hv.y, wcol[4 * kq + 1], acc[j]);
          acc[j] = fmaf(hv.z, wcol[4 * kq + 2], acc[j]);
          acc[j] = fmaf(hv.w, wcol[4 * kq + 3], acc[j]);
        }
      }
      #pragma unroll
      for (int j = 0; j < 8; ++j) y0s[(grp * 8 + j) * 40 + c] = fmaxf(acc[j] + bias, 0.f);
    }
  }
  __syncthreads();
  {  // y1 = relu(y0@Wr1 + br1)
    int c = tid % 20, grp = tid / 20;  // 0..15
    if (grp < 5) {
      float wcol[40];
      #pragma unroll
      for (int kk = 0; kk < 40; ++kk) wcol[kk] = Wr1[kk * 20 + c];
      float bias = br1[c];
      float acc[8] = {};
      #pragma unroll
      for (int j = 0; j < 8; ++j) {
        const float4* r4 = reinterpret_cast<const float4*>(y0s + (grp * 8 + j) * 40);
        #pragma unroll
        for (int kq = 0; kq < 10; ++kq) {
          float4 hv = r4[kq];
          acc[j] = fmaf(hv.x, wcol[4 * kq + 0], acc[j]);
          acc[j] = fmaf(hv.y, wcol[4 * kq + 1], acc[j]);
          acc[j] = fmaf(hv.z, wcol[4 * kq + 2], acc[j]);
          acc[j] = fmaf(hv.w, wcol[4 * kq + 3], acc[j]);
        }
      }
      #pragma unroll
      for (int j = 0; j < 8; ++j) y1s[(grp * 8 + j) * 20 + c] = fmaxf(acc[j] + bias, 0.f);
    }
  }
  __syncthreads();
  {  // y2 = y1@Wr2 + br2
    int c = tid % 64, grp = tid / 64;  // 0..4
    float wcol[20];
    #pragma unroll
    for (int kk = 0; kk < 20; ++kk) wcol[kk] = Wr2[kk * 64 + c];
    float bias = br2[c];
    float acc[8] = {};
    #pragma unroll
    for (int j = 0; j < 8; ++j) {
      const float4* r4 = reinterpret_cast<const float4*>(y1s + (grp * 8 + j) * 20);
      #pragma unroll
      for (int kq = 0; kq < 5; ++kq) {
        float4 hv = r4[kq];
        acc[j] = fmaf(hv.x, wcol[4 * kq + 0], acc[j]);
        acc[j] = fmaf(hv.y, wcol[4 * kq + 1], acc[j]);
        acc[j] = fmaf(hv.z, wcol[4 * kq + 2], acc[j]);
        acc[j] = fmaf(hv.w, wcol[4 * kq + 3], acc[j]);
      }
    }
    #pragma unroll
    for (int j = 0; j < 8; ++j) y2s[(grp * 8 + j) * 64 + c] = acc[j] + bias;
  }
  __syncthreads();
  {  // out: cc = y2@Wc, beta = y2@Wb + bb
    int c = tid % 4, p = tid / 4;
    if (p < 40) {
      float wcol[64];
      if (c < 3) {
        #pragma unroll
        for (int kk = 0; kk < 64; ++kk) wcol[kk] = Wc[kk * 3 + c];
      } else {
        #pragma unroll
        for (int kk = 0; kk < 64; ++kk) wcol[kk] = Wb[kk];
      }
      float acc = 0.f;
      #pragma unroll
      for (int kk = 0; kk < 64; ++kk) acc = fmaf(y2s[p * 64 + kk], wcol[kk], acc);
      if (c == 3) acc += bb[0];
      out[(p0 + p) * 4 + c] = acc;
    }
  }
}

extern "C" void kernel_launch(void* const* d_in, const int* in_sizes, int n_in,
                              void* d_out, int out_size, void* d_ws, size_t ws_size,
                              hipStream_t stream) {
  const float* hf = (const float*)d_in[0];
  const float* gamma = (const float*)d_in[1];
  const float* beta = (const float*)d_in[2];
  const float* We = (const float*)d_in[3];
  const float* be = (const float*)d_in[4];
  const float* Wq = (const float*)d_in[5];
  const float* Wk = (const float*)d_in[6];
  const float* Wv = (const float*)d_in[7];
  const float* Wo = (const float*)d_in[8];
  const float* bo = (const float*)d_in[9];
  const float* W1 = (const float*)d_in[10];
  const float* b1 = (const float*)d_in[11];
  const float* W2 = (const float*)d_in[12];
  const float* b2 = (const float*)d_in[13];
  const float* Wr0 = (const float*)d_in[14];
  const float* br0 = (const float*)d_in[15];
  const float* Wr1 = (const float*)d_in[16];
  const float* br1 = (const float*)d_in[17];
  const float* Wr2 = (const float*)d_in[18];
  const float* br2 = (const float*)d_in[19];
  const float* Wc = (const float*)d_in[20];
  const float* Wb = (const float*)d_in[21];
  const float* bb = (const float*)d_in[22];
  float* out = (float*)d_out;

  // Workspace budget: 3 big f32 buffers (hA,kbuf,vbuf) + nbr + weights ~= 256.4 MB (r7-proven; r8's 4th buffer overflowed)
  char* wsp = (char*)d_ws;
  int* nbr = (int*)wsp;            wsp += (size_t)256000 * 8 * 4;
  float* hA = (float*)wsp;         wsp += (size_t)256000 * 80 * 4;
  float* kbuf = (float*)wsp;       wsp += (size_t)256000 * 80 * 4;
  float* vbuf = (float*)wsp;       wsp += (size_t)256000 * 80 * 4;
  float* partial = (float*)wsp;    wsp += (size_t)1000 * 18 * 4;
  float* stats = (float*)wsp;      wsp += 128;
  unsigned short* WqH = (unsigned short*)wsp; wsp += (size_t)10 * 7680 * 2;
  unsigned short* WqL = (unsigned short*)wsp; wsp += (size_t)10 * 7680 * 2;
  unsigned short* WkH = (unsigned short*)wsp; wsp += (size_t)10 * 7680 * 2;
  unsigned short* WkL = (unsigned short*)wsp; wsp += (size_t)10 * 7680 * 2;
  unsigned short* WvH = (unsigned short*)wsp; wsp += (size_t)10 * 7680 * 2;
  unsigned short* WvL = (unsigned short*)wsp; wsp += (size_t)10 * 7680 * 2;
  unsigned short* WoH = (unsigned short*)wsp; wsp += (size_t)10 * 7680 * 2;
  unsigned short* WoL = (unsigned short*)wsp; wsp += (size_t)10 * 7680 * 2;
  unsigned short* W1H = (unsigned short*)wsp; wsp += (size_t)10 * 15360 * 2;
  unsigned short* W1L = (unsigned short*)wsp; wsp += (size_t)10 * 15360 * 2;
  unsigned short* W2H = (unsigned short*)wsp; wsp += (size_t)10 * 12800 * 2;
  unsigned short* W2L = (unsigned short*)wsp; wsp += (size_t)10 * 12800 * 2;

  knn_kernel<<<2048, 128, 0, stream>>>(hf, nbr);
  bn_stat1<<<1000, 256, 0, stream>>>(hf, partial);
  bn_stat2<<<1, 256, 0, stream>>>(partial, stats);
  split_tr<<<10, 256, 0, stream>>>(Wq, WqH, WqL, 80, 80, 96);
  split_tr<<<10, 256, 0, stream>>>(Wk, WkH, WkL, 80, 80, 96);
  split_tr<<<10, 256, 0, stream>>>(Wv, WvH, WvL, 80, 80, 96);
  split_tr<<<10, 256, 0, stream>>>(Wo, WoH, WoL, 80, 80, 96);
  split_tr<<<10, 256, 0, stream>>>(W1, W1H, W1L, 80, 160, 96);
  split_tr<<<10, 256, 0, stream>>>(W2, W2H, W2L, 160, 80, 160);
  embed_kernel<<<6400, 320, 0, stream>>>(hf, stats, gamma, beta, We, be, hA);
  for (int l = 0; l < 10; ++l) {
    kv_kernel<<<6400, 320, 0, stream>>>(hA, WkH + (size_t)l * 7680, WkL + (size_t)l * 7680,
                                        WvH + (size_t)l * 7680, WvL + (size_t)l * 7680, kbuf, vbuf);
    battn_kernel<<<3328, 320, 0, stream>>>(hA, kbuf, vbuf, nbr,
                                           WqH + (size_t)l * 7680, WqL + (size_t)l * 7680,
                                           WoH + (size_t)l * 7680, WoL + (size_t)l * 7680, bo + (size_t)l * 80,
                                           W1H + (size_t)l * 15360, W1L + (size_t)l * 15360, b1 + (size_t)l * 160,
                                           W2H + (size_t)l * 12800, W2L + (size_t)l * 12800, b2 + (size_t)l * 80, hA);
  }
  readout_kernel<<<6400, 320, 0, stream>>>(hA, Wr0, br0, Wr1, br1, Wr2, br2, Wc, Wb, bb, out);
}

// Round 10
// 3423.848 us; speedup vs baseline: 1.3150x; 1.3150x over previous
//
#include <hip/hip_runtime.h>
#include <cstdint>
#include <cstddef>

// G=256 graphs, NP=1000 points, K=8 neighbors, H=8 heads, DH=10, D=80, NL=10 layers
// GEMMs via split-bf16 MFMA: x = hi + lo (bf16 each); C = Ahi*Bhi + Ahi*Blo + Alo*Bhi (~f32 accuracy).
// r10 = r7 structure (proven 3.57ms) + h-residual reg prefetch + unified XCD swizzle + knn unroll-8.

typedef __attribute__((ext_vector_type(8))) short short8v;
typedef __attribute__((ext_vector_type(4))) float f32x4;

#define MFMA16(ACC, A, B) ACC = __builtin_amdgcn_mfma_f32_16x16x32_bf16(A, B, ACC, 0, 0, 0)
#define MF3(ACC, AH, AL, BH, BL) { MFMA16(ACC, AH, BH); MFMA16(ACC, AH, BL); MFMA16(ACC, AL, BH); }

__device__ __forceinline__ void splitbf(float x, unsigned short& hi, unsigned short& lo) {
  unsigned u = __float_as_uint(x);
  unsigned r = u + 0x7FFFu + ((u >> 16) & 1u);
  hi = (unsigned short)(r >> 16);
  float hf = __uint_as_float(((unsigned)hi) << 16);
  float lf = x - hf;
  unsigned u2 = __float_as_uint(lf);
  unsigned r2 = u2 + 0x7FFFu + ((u2 >> 16) & 1u);
  lo = (unsigned short)(r2 >> 16);
}

__device__ __forceinline__ float bf2f(unsigned short v) {
  return __uint_as_float(((unsigned)v) << 16);
}

// ---------------- KNN: 256 thr / 2 octants per block, unroll-8, exact order + stable tie-break ----------------
__global__ __launch_bounds__(256) void knn_kernel(const float* __restrict__ hf, int* __restrict__ nbr) {
  __shared__ __align__(16) float cs[3000];
  int b = blockIdx.x;
  int g = b >> 2;
  for (int i = threadIdx.x; i < 3000; i += 256) {
    cs[i] = hf[((size_t)g * 1000 + (i / 3)) * 9 + (i % 3)];
  }
  __syncthreads();
  int tid = threadIdx.x;
  int lane = tid & 127;
  int q = ((b & 3) << 1) + (tid >> 7);  // 8 octants of 125 points
  if (lane < 125) {
    int n = q * 125 + lane;
    float cx = cs[n * 3 + 0], cy = cs[n * 3 + 1], cz = cs[n * 3 + 2];
    float bd[8];
    int bi[8];
    #pragma unroll
    for (int q2 = 0; q2 < 8; ++q2) { bd[q2] = 3.402823466e38f; bi[q2] = 0; }
    for (int j = 0; j < 1000; j += 8) {
      const float4* base = reinterpret_cast<const float4*>(cs + j * 3);
      float4 a0 = base[0], a1 = base[1], a2 = base[2], a3 = base[3], a4 = base[4], a5 = base[5];
      float d2v[8];
      {
        float dx = __fsub_rn(cx, a0.x), dy = __fsub_rn(cy, a0.y), dz = __fsub_rn(cz, a0.z);
        d2v[0] = __fadd_rn(__fadd_rn(__fmul_rn(dx, dx), __fmul_rn(dy, dy)), __fmul_rn(dz, dz));
      }
      {
        float dx = __fsub_rn(cx, a0.w), dy = __fsub_rn(cy, a1.x), dz = __fsub_rn(cz, a1.y);
        d2v[1] = __fadd_rn(__fadd_rn(__fmul_rn(dx, dx), __fmul_rn(dy, dy)), __fmul_rn(dz, dz));
      }
      {
        float dx = __fsub_rn(cx, a1.z), dy = __fsub_rn(cy, a1.w), dz = __fsub_rn(cz, a2.x);
        d2v[2] = __fadd_rn(__fadd_rn(__fmul_rn(dx, dx), __fmul_rn(dy, dy)), __fmul_rn(dz, dz));
      }
      {
        float dx = __fsub_rn(cx, a2.y), dy = __fsub_rn(cy, a2.z), dz = __fsub_rn(cz, a2.w);
        d2v[3] = __fadd_rn(__fadd_rn(__fmul_rn(dx, dx), __fmul_rn(dy, dy)), __fmul_rn(dz, dz));
      }
      {
        float dx = __fsub_rn(cx, a3.x), dy = __fsub_rn(cy, a3.y), dz = __fsub_rn(cz, a3.z);
        d2v[4] = __fadd_rn(__fadd_rn(__fmul_rn(dx, dx), __fmul_rn(dy, dy)), __fmul_rn(dz, dz));
      }
      {
        float dx = __fsub_rn(cx, a3.w), dy = __fsub_rn(cy, a4.x), dz = __fsub_rn(cz, a4.y);
        d2v[5] = __fadd_rn(__fadd_rn(__fmul_rn(dx, dx), __fmul_rn(dy, dy)), __fmul_rn(dz, dz));
      }
      {
        float dx = __fsub_rn(cx, a4.z), dy = __fsub_rn(cy, a4.w), dz = __fsub_rn(cz, a5.x);
        d2v[6] = __fadd_rn(__fadd_rn(__fmul_rn(dx, dx), __fmul_rn(dy, dy)), __fmul_rn(dz, dz));
      }
      {
        float dx = __fsub_rn(cx, a5.y), dy = __fsub_rn(cy, a5.z), dz = __fsub_rn(cz, a5.w);
        d2v[7] = __fadd_rn(__fadd_rn(__fmul_rn(dx, dx), __fmul_rn(dy, dy)), __fmul_rn(dz, dz));
      }
      #pragma unroll
      for (int u = 0; u < 8; ++u) {
        float d2 = d2v[u];
        if (d2 < bd[7]) {
          bd[7] = d2; bi[7] = j + u;
          #pragma unroll
          for (int q2 = 7; q2 >= 1; --q2) {
            if (bd[q2] < bd[q2 - 1]) {  // strict: lower index first on ties (top_k semantics)
              float tf = bd[q2]; bd[q2] = bd[q2 - 1]; bd[q2 - 1] = tf;
              int ti = bi[q2]; bi[q2] = bi[q2 - 1]; bi[q2 - 1] = ti;
            }
          }
        }
      }
    }
    #pragma unroll
    for (int kk = 0; kk < 8; ++kk) nbr[((size_t)g * 1000 + n) * 8 + kk] = bi[kk];
  }
}

// ---------------- BatchNorm stats (deterministic two-stage) ----------------
__global__ __launch_bounds__(256) void bn_stat1(const float* __restrict__ hf, float* __restrict__ partial) {
  __shared__ float red[4][18];
  int row = blockIdx.x * 256 + threadIdx.x;
  float s[9], ss[9];
  #pragma unroll
  for (int f = 0; f < 9; ++f) {
    float v = hf[(size_t)row * 9 + f];
    s[f] = v;
    ss[f] = v * v;
  }
  for (int off = 32; off > 0; off >>= 1) {
    #pragma unroll
    for (int f = 0; f < 9; ++f) {
      s[f] += __shfl_down(s[f], off);
      ss[f] += __shfl_down(ss[f], off);
    }
  }
  int wid = threadIdx.x >> 6, lane = threadIdx.x & 63;
  if (lane == 0) {
    #pragma unroll
    for (int f = 0; f < 9; ++f) { red[wid][f] = s[f]; red[wid][9 + f] = ss[f]; }
  }
  __syncthreads();
  if (threadIdx.x < 18) {
    partial[(size_t)blockIdx.x * 18 + threadIdx.x] =
        red[0][threadIdx.x] + red[1][threadIdx.x] + red[2][threadIdx.x] + red[3][threadIdx.x];
  }
}

__global__ __launch_bounds__(256) void bn_stat2(const float* __restrict__ partial, float* __restrict__ stats) {
  __shared__ double sd[9][28], qd[9][28];
  int tid = threadIdx.x;
  if (tid < 252) {
    int f = tid % 9, gq = tid / 9;
    double s = 0.0, q = 0.0;
    for (int b = gq; b < 1000; b += 28) {
      s += (double)partial[b * 18 + f];
      q += (double)partial[b * 18 + 9 + f];
    }
    sd[f][gq] = s;
    qd[f][gq] = q;
  }
  __syncthreads();
  if (tid < 9) {
    double s = 0.0, q = 0.0;
    for (int g2 = 0; g2 < 28; ++g2) { s += sd[tid][g2]; q += qd[tid][g2]; }
    double mu = s / 256000.0;
    double var = q / 256000.0 - mu * mu;
    stats[tid] = (float)mu;
    stats[9 + tid] = (float)(1.0 / sqrt(var + 1e-5));
  }
}

// ---------------- Weight split-transpose: W[R][C] -> BT_hi/lo[C][KS] bf16, k-pad zeroed ----------------
__global__ __launch_bounds__(256) void split_tr(const float* __restrict__ src, unsigned short* __restrict__ dhi,
                                                unsigned short* __restrict__ dlo, int R, int C, int KS) {
  const float* s = src + (size_t)blockIdx.x * R * C;
  unsigned short* dh = dhi + (size_t)blockIdx.x * C * KS;
  unsigned short* dl = dlo + (size_t)blockIdx.x * C * KS;
  int n = C * KS;
  for (int i = threadIdx.x; i < n; i += 256) {
    int c = i / KS, kk = i % KS;
    float v = (kk < R) ? s[kk * C + c] : 0.f;
    unsigned short h, l;
    splitbf(v, h, l);
    dh[i] = h;
    dl[i] = l;
  }
}

// ---------------- Embed: normalize + (9->80) ----------------
__global__ __launch_bounds__(320) void embed_kernel(const float* __restrict__ hf, const float* __restrict__ stats,
                                                    const float* __restrict__ gamma, const float* __restrict__ beta,
                                                    const float* __restrict__ We, const float* __restrict__ be,
                                                    float* __restrict__ h) {
  __shared__ __align__(16) float xs[40 * 9];
  size_t p0 = (size_t)blockIdx.x * 40;
  for (int i = threadIdx.x; i < 360; i += 320) {
    int f = i % 9;
    float x = hf[p0 * 9 + i];
    xs[i] = (x - stats[f]) * stats[9 + f] * gamma[f] + beta[f];
  }
  __syncthreads();
  int c = threadIdx.x % 80, pg = threadIdx.x / 80;
  float we[9];
  #pragma unroll
  for (int f = 0; f < 9; ++f) we[f] = We[f * 80 + c];
  float bias = be[c];
  for (int pp = 0; pp < 10; ++pp) {
    int p = pg * 10 + pp;
    float acc = 0.f;
    #pragma unroll
    for (int f = 0; f < 9; ++f) acc = fmaf(xs[p * 9 + f], we[f], acc);
    h[(p0 + p) * 80 + c] = acc + bias;
  }
}

// ---------------- K,V projection via split-bf16 MFMA (XCD-swizzled to match battn) ----------------
__global__ __launch_bounds__(320) void kv_kernel(const float* __restrict__ h,
                                                 const unsigned short* __restrict__ WkH, const unsigned short* __restrict__ WkL,
                                                 const unsigned short* __restrict__ WvH, const unsigned short* __restrict__ WvL,
                                                 float* __restrict__ kb, float* __restrict__ vb) {
  __shared__ __align__(16) unsigned short ahi[48 * 104];
  __shared__ __align__(16) unsigned short alo[48 * 104];
  int b = blockIdx.x;
  int xcd = b & 7;
  int r = b >> 3;
  int graph = (xcd << 5) + (r / 25);
  int jb = r % 25;
  size_t p0 = (size_t)graph * 1000 + (size_t)jb * 40;
  int tid = threadIdx.x;
  int lane = tid & 63, wv = tid >> 6;
  int fr = lane & 15, fq = lane >> 4;
  for (int i = tid; i < 800; i += 320) {
    int row = i / 20, kq = i % 20;
    float4 v = reinterpret_cast<const float4*>(h + (p0 + row) * 80)[kq];
    unsigned short h0, l0, h1, l1, h2, l2, h3, l3;
    splitbf(v.x, h0, l0); splitbf(v.y, h1, l1); splitbf(v.z, h2, l2); splitbf(v.w, h3, l3);
    int off = row * 104 + kq * 4;
    *reinterpret_cast<unsigned*>(&ahi[off]) = (unsigned)h0 | ((unsigned)h1 << 16);
    *reinterpret_cast<unsigned*>(&ahi[off + 2]) = (unsigned)h2 | ((unsigned)h3 << 16);
    *reinterpret_cast<unsigned*>(&alo[off]) = (unsigned)l0 | ((unsigned)l1 << 16);
    *reinterpret_cast<unsigned*>(&alo[off + 2]) = (unsigned)l2 | ((unsigned)l3 << 16);
  }
  for (int i = tid; i < 384; i += 320) {
    int row = i >> 3, kk = 80 + ((i & 7) << 1);
    int off = row * 104 + kk;
    *reinterpret_cast<unsigned*>(&ahi[off]) = 0u;
    *reinterpret_cast<unsigned*>(&alo[off]) = 0u;
  }
  __syncthreads();
  int bcol = wv * 16 + fr;
  f32x4 ck0 = {0.f, 0.f, 0.f, 0.f}, ck1 = ck0, ck2 = ck0;
  f32x4 cv0 = ck0, cv1 = ck0, cv2 = ck0;
  #pragma unroll
  for (int ks = 0; ks < 3; ++ks) {
    int boff = bcol * 96 + ks * 32 + fq * 8;
    short8v bkh = *reinterpret_cast<const short8v*>(WkH + boff);
    short8v bkl = *reinterpret_cast<const short8v*>(WkL + boff);
    short8v bvh = *reinterpret_cast<const short8v*>(WvH + boff);
    short8v bvl = *reinterpret_cast<const short8v*>(WvL + boff);
    int a0 = (0 * 16 + fr) * 104 + ks * 32 + fq * 8;
    int a1 = (1 * 16 + fr) * 104 + ks * 32 + fq * 8;
    int a2 = (2 * 16 + fr) * 104 + ks * 32 + fq * 8;
    short8v ah0 = *reinterpret_cast<const short8v*>(ahi + a0);
    short8v al0 = *reinterpret_cast<const short8v*>(alo + a0);
    MF3(ck0, ah0, al0, bkh, bkl); MF3(cv0, ah0, al0, bvh, bvl);
    short8v ah1 = *reinterpret_cast<const short8v*>(ahi + a1);
    short8v al1 = *reinterpret_cast<const short8v*>(alo + a1);
    MF3(ck1, ah1, al1, bkh, bkl); MF3(cv1, ah1, al1, bvh, bvl);
    short8v ah2 = *reinterpret_cast<const short8v*>(ahi + a2);
    short8v al2 = *reinterpret_cast<const short8v*>(alo + a2);
    MF3(ck2, ah2, al2, bkh, bkl); MF3(cv2, ah2, al2, bvh, bvl);
  }
  #pragma unroll
  for (int j = 0; j < 4; ++j) {
    int r0 = fq * 4 + j;
    kb[(p0 + r0) * 80 + bcol] = ck0[j];
    vb[(p0 + r0) * 80 + bcol] = cv0[j];
    int r1 = 16 + r0;
    kb[(p0 + r1) * 80 + bcol] = ck1[j];
    vb[(p0 + r1) * 80 + bcol] = cv1[j];
    int r2 = 32 + r0;
    if (r2 < 40) {
      kb[(p0 + r2) * 80 + bcol] = ck2[j];
      vb[(p0 + r2) * 80 + bcol] = cv2[j];
    }
  }
}

// ---------------- Fused layer: q MFMA + attention(f32) + Wo MFMA + FFN MFMA; h-residual prefetched ----------------
__global__ __launch_bounds__(320) void battn_kernel(const float* __restrict__ h, const float* __restrict__ kb,
                                                    const float* __restrict__ vb, const int* __restrict__ nbr,
                                                    const unsigned short* __restrict__ WqH, const unsigned short* __restrict__ WqL,
                                                    const unsigned short* __restrict__ WoH, const unsigned short* __restrict__ WoL,
                                                    const float* __restrict__ bo,
                                                    const unsigned short* __restrict__ W1H, const unsigned short* __restrict__ W1L,
                                                    const float* __restrict__ b1,
                                                    const unsigned short* __restrict__ W2H, const unsigned short* __restrict__ W2L,
                                                    const float* __restrict__ b2, float* __restrict__ hout) {
  __shared__ __align__(16) unsigned short ahi[48 * 168];  // split buffer: h -> q -> attn -> h2 -> ts
  __shared__ __align__(16) unsigned short alo[48 * 168];
  int b = blockIdx.x;
  int xcd = b & 7;
  int r = b >> 3;
  int graph = (xcd << 5) + (r / 25);
  int jb = r % 25;
  size_t gbase = (size_t)graph * 1000;
  size_t pbase = gbase + (size_t)jb * 40;
  int tid = threadIdx.x;
  int lane = tid & 63, wv = tid >> 6;
  int fr = lane & 15, fq = lane >> 4;
  int bcol = wv * 16 + fr;
  int pA = tid >> 3, hhA = tid & 7;
  // prefetch neighbor indices + h residual (consumed in h2 phase, 5 phases later: latency hidden)
  int nb[8];
  #pragma unroll
  for (int kk = 0; kk < 8; ++kk) nb[kk] = nbr[(pbase + pA) * 8 + kk];
  float hres0[4], hres1[4], hres2[4];
  #pragma unroll
  for (int j = 0; j < 4; ++j) {
    int r0 = fq * 4 + j;
    hres0[j] = h[(pbase + r0) * 80 + bcol];
    hres1[j] = h[(pbase + 16 + r0) * 80 + bcol];
    int r2 = 32 + r0;
    hres2[j] = (r2 < 40) ? h[(pbase + r2) * 80 + bcol] : 0.f;
  }
  // stage + split h (rows 0..39, cols 0..79); zero pad cols 80..95 rows 0..47
  for (int i = tid; i < 800; i += 320) {
    int row = i / 20, kq = i % 20;
    float4 v = reinterpret_cast<const float4*>(h + (pbase + row) * 80)[kq];
    unsigned short h0, l0, h1, l1, h2_, l2, h3, l3;
    splitbf(v.x, h0, l0); splitbf(v.y, h1, l1); splitbf(v.z, h2_, l2); splitbf(v.w, h3, l3);
    int off = row * 168 + kq * 4;
    *reinterpret_cast<unsigned*>(&ahi[off]) = (unsigned)h0 | ((unsigned)h1 << 16);
    *reinterpret_cast<unsigned*>(&ahi[off + 2]) = (unsigned)h2_ | ((unsigned)h3 << 16);
    *reinterpret_cast<unsigned*>(&alo[off]) = (unsigned)l0 | ((unsigned)l1 << 16);
    *reinterpret_cast<unsigned*>(&alo[off + 2]) = (unsigned)l2 | ((unsigned)l3 << 16);
  }
  for (int i = tid; i < 384; i += 320) {
    int row = i >> 3, kk = 80 + ((i & 7) << 1);
    int off = row * 168 + kk;
    *reinterpret_cast<unsigned*>(&ahi[off]) = 0u;
    *reinterpret_cast<unsigned*>(&alo[off]) = 0u;
  }
  __syncthreads();
  // ---- q = h @ Wq (MFMA) -> regs ----
  f32x4 q0 = {0.f, 0.f, 0.f, 0.f}, q1 = q0, q2 = q0;
  {
    #pragma unroll
    for (int ks = 0; ks < 3; ++ks) {
      int boff = bcol * 96 + ks * 32 + fq * 8;
      short8v bh = *reinterpret_cast<const short8v*>(WqH + boff);
      short8v bl = *reinterpret_cast<const short8v*>(WqL + boff);
      int a0 = (0 * 16 + fr) * 168 + ks * 32 + fq * 8;
      int a1 = (1 * 16 + fr) * 168 + ks * 32 + fq * 8;
      int a2 = (2 * 16 + fr) * 168 + ks * 32 + fq * 8;
      short8v ah0 = *reinterpret_cast<const short8v*>(ahi + a0);
      short8v al0 = *reinterpret_cast<const short8v*>(alo + a0);
      MF3(q0, ah0, al0, bh, bl);
      short8v ah1 = *reinterpret_cast<const short8v*>(ahi + a1);
      short8v al1 = *reinterpret_cast<const short8v*>(alo + a1);
      MF3(q1, ah1, al1, bh, bl);
      short8v ah2 = *reinterpret_cast<const short8v*>(ahi + a2);
      short8v al2 = *reinterpret_cast<const short8v*>(alo + a2);
      MF3(q2, ah2, al2, bh, bl);
    }
  }
  __syncthreads();  // all q-MFMA reads of h split done
  // ---- write q split over dead h split (cols 0..79) ----
  {
    #pragma unroll
    for (int j = 0; j < 4; ++j) {
      unsigned short hh_, ll_;
      int r0 = fq * 4 + j;
      splitbf(q0[j], hh_, ll_);
      ahi[r0 * 168 + bcol] = hh_; alo[r0 * 168 + bcol] = ll_;
      int r1 = 16 + r0;
      splitbf(q1[j], hh_, ll_);
      ahi[r1 * 168 + bcol] = hh_; alo[r1 * 168 + bcol] = ll_;
      int r2 = 32 + r0;
      if (r2 < 40) {
        splitbf(q2[j], hh_, ll_);
        ahi[r2 * 168 + bcol] = hh_; alo[r2 * 168 + bcol] = ll_;
      }
    }
  }
  __syncthreads();
  // ---- attention (f32): q = hi+lo; writes attn split over own q slice ----
  {
    int p = pA, hh = hhA;
    float qv[10];
    #pragma unroll
    for (int d2 = 0; d2 < 5; ++d2) {
      int off = p * 168 + hh * 10 + 2 * d2;
      unsigned uh = *reinterpret_cast<const unsigned*>(&ahi[off]);
      unsigned ul = *reinterpret_cast<const unsigned*>(&alo[off]);
      qv[2 * d2] = bf2f((unsigned short)uh) + bf2f((unsigned short)ul);
      qv[2 * d2 + 1] = bf2f((unsigned short)(uh >> 16)) + bf2f((unsigned short)(ul >> 16));
    }
    float sv[8];
    float denom = 0.f;
    #pragma unroll
    for (int kk = 0; kk < 8; ++kk) {
      const float2* kr = reinterpret_cast<const float2*>(kb + (gbase + nb[kk]) * 80 + hh * 10);
      float acc = 0.f;
      #pragma unroll
      for (int d2 = 0; d2 < 5; ++d2) {
        float2 kv2 = kr[d2];
        acc = fmaf(qv[2 * d2], kv2.x, acc);
        acc = fmaf(qv[2 * d2 + 1], kv2.y, acc);
      }
      float s = acc * 0.31622776601683794f;
      s = fminf(fmaxf(s, -5.f), 5.f);
      s = expf(s);
      sv[kk] = s;
      denom += s;
    }
    float wV[10] = {0, 0, 0, 0, 0, 0, 0, 0, 0, 0};
    #pragma unroll
    for (int kk = 0; kk < 8; ++kk) {
      const float2* vr = reinterpret_cast<const float2*>(vb + (gbase + nb[kk]) * 80 + hh * 10);
      #pragma unroll
      for (int d2 = 0; d2 < 5; ++d2) {
        float2 vv = vr[d2];
        wV[2 * d2] = fmaf(sv[kk], vv.x, wV[2 * d2]);
        wV[2 * d2 + 1] = fmaf(sv[kk], vv.y, wV[2 * d2 + 1]);
      }
    }
    float dn = denom + 1e-6f;
    #pragma unroll
    for (int d2 = 0; d2 < 5; ++d2) {
      float x0 = wV[2 * d2] / dn;
      float x1 = wV[2 * d2 + 1] / dn;
      unsigned short h0, l0, h1, l1;
      splitbf(x0, h0, l0); splitbf(x1, h1, l1);
      int off = p * 168 + hh * 10 + 2 * d2;
      *reinterpret_cast<unsigned*>(&ahi[off]) = (unsigned)h0 | ((unsigned)h1 << 16);
      *reinterpret_cast<unsigned*>(&alo[off]) = (unsigned)l0 | ((unsigned)l1 << 16);
    }
  }
  __syncthreads();
  // ---- Wo MFMA (reads attn split) -> o regs ----
  f32x4 o0 = {0.f, 0.f, 0.f, 0.f}, o1 = o0, o2 = o0;
  {
    #pragma unroll
    for (int ks = 0; ks < 3; ++ks) {
      int boff = bcol * 96 + ks * 32 + fq * 8;
      short8v bh = *reinterpret_cast<const short8v*>(WoH + boff);
      short8v bl = *reinterpret_cast<const short8v*>(WoL + boff);
      int a0 = (0 * 16 + fr) * 168 + ks * 32 + fq * 8;
      int a1 = (1 * 16 + fr) * 168 + ks * 32 + fq * 8;
      int a2 = (2 * 16 + fr) * 168 + ks * 32 + fq * 8;
      short8v ah0 = *reinterpret_cast<const short8v*>(ahi + a0);
      short8v al0 = *reinterpret_cast<const short8v*>(alo + a0);
      MF3(o0, ah0, al0, bh, bl);
      short8v ah1 = *reinterpret_cast<const short8v*>(ahi + a1);
      short8v al1 = *reinterpret_cast<const short8v*>(alo + a1);
      MF3(o1, ah1, al1, bh, bl);
      short8v ah2 = *reinterpret_cast<const short8v*>(ahi + a2);
      short8v al2 = *reinterpret_cast<const short8v*>(alo + a2);
      MF3(o2, ah2, al2, bh, bl);
    }
  }
  __syncthreads();  // all Wo reads done before h2 overwrites
  // ---- h2 = hres(prefetched) + attn@Wo + bo: f32 in regs, write split ----
  {
    float bias = bo[bcol];
    #pragma unroll
    for (int j = 0; j < 4; ++j) {
      unsigned short hh_, ll_;
      int r0 = fq * 4 + j;
      o0[j] = hres0[j] + o0[j] + bias;
      splitbf(o0[j], hh_, ll_);
      ahi[r0 * 168 + bcol] = hh_; alo[r0 * 168 + bcol] = ll_;
      int r1 = 16 + r0;
      o1[j] = hres1[j] + o1[j] + bias;
      splitbf(o1[j], hh_, ll_);
      ahi[r1 * 168 + bcol] = hh_; alo[r1 * 168 + bcol] = ll_;
      int r2 = 32 + r0;
      if (r2 < 40) {
        o2[j] = hres2[j] + o2[j] + bias;
        splitbf(o2[j], hh_, ll_);
        ahi[r2 * 168 + bcol] = hh_; alo[r2 * 168 + bcol] = ll_;
      }
    }
  }
  __syncthreads();
  // ---- W1 MFMA: ts = relu(h2 @ W1 + b1), N=160 -> two col-tiles per wave ----
  f32x4 t00 = {0.f, 0.f, 0.f, 0.f}, t01 = t00, t02 = t00;
  f32x4 t10 = t00, t11 = t00, t12 = t00;
  {
    int bc0 = wv * 16 + fr, bc1 = (wv + 5) * 16 + fr;
    #pragma unroll
    for (int ks = 0; ks < 3; ++ks) {
      int b0 = bc0 * 96 + ks * 32 + fq * 8;
      int b1o = bc1 * 96 + ks * 32 + fq * 8;
      short8v bh0 = *reinterpret_cast<const short8v*>(W1H + b0);
      short8v bl0 = *reinterpret_cast<const short8v*>(W1L + b0);
      short8v bh1 = *reinterpret_cast<const short8v*>(W1H + b1o);
      short8v bl1 = *reinterpret_cast<const short8v*>(W1L + b1o);
      int a0 = (0 * 16 + fr) * 168 + ks * 32 + fq * 8;
      int a1 = (1 * 16 + fr) * 168 + ks * 32 + fq * 8;
      int a2 = (2 * 16 + fr) * 168 + ks * 32 + fq * 8;
      short8v ah0 = *reinterpret_cast<const short8v*>(ahi + a0);
      short8v al0 = *reinterpret_cast<const short8v*>(alo + a0);
      MF3(t00, ah0, al0, bh0, bl0); MF3(t10, ah0, al0, bh1, bl1);
      short8v ah1 = *reinterpret_cast<const short8v*>(ahi + a1);
      short8v al1 = *reinterpret_cast<const short8v*>(alo + a1);
      MF3(t01, ah1, al1, bh0, bl0); MF3(t11, ah1, al1, bh1, bl1);
      short8v ah2 = *reinterpret_cast<const short8v*>(ahi + a2);
      short8v al2 = *reinterpret_cast<const short8v*>(alo + a2);
      MF3(t02, ah2, al2, bh0, bl0); MF3(t12, ah2, al2, bh1, bl1);
    }
  }
  __syncthreads();  // all W1 reads of h2 split done
  // ---- ts epilogue: relu + split -> cols 0..159 ----
  {
    int bc0 = wv * 16 + fr, bc1 = (wv + 5) * 16 + fr;
    float bias0 = b1[bc0], bias1 = b1[bc1];
    #pragma unroll
    for (int j = 0; j < 4; ++j) {
      unsigned short hh_, ll_;
      int r0 = fq * 4 + j;
      float t = fmaxf(t00[j] + bias0, 0.f);
      splitbf(t, hh_, ll_); ahi[r0 * 168 + bc0] = hh_; alo[r0 * 168 + bc0] = ll_;
      t = fmaxf(t10[j] + bias1, 0.f);
      splitbf(t, hh_, ll_); ahi[r0 * 168 + bc1] = hh_; alo[r0 * 168 + bc1] = ll_;
      int r1 = 16 + r0;
      t = fmaxf(t01[j] + bias0, 0.f);
      splitbf(t, hh_, ll_); ahi[r1 * 168 + bc0] = hh_; alo[r1 * 168 + bc0] = ll_;
      t = fmaxf(t11[j] + bias1, 0.f);
      splitbf(t, hh_, ll_); ahi[r1 * 168 + bc1] = hh_; alo[r1 * 168 + bc1] = ll_;
      int r2 = 32 + r0;
      if (r2 < 40) {
        t = fmaxf(t02[j] + bias0, 0.f);
        splitbf(t, hh_, ll_); ahi[r2 * 168 + bc0] = hh_; alo[r2 * 168 + bc0] = ll_;
        t = fmaxf(t12[j] + bias1, 0.f);
        splitbf(t, hh_, ll_); ahi[r2 * 168 + bc1] = hh_; alo[r2 * 168 + bc1] = ll_;
      }
    }
  }
  __syncthreads();
  // ---- W2 MFMA: hout = h2(regs) + ts @ W2 + b2, K=160 ----
  {
    f32x4 c0 = {0.f, 0.f, 0.f, 0.f}, c1 = c0, c2 = c0;
    #pragma unroll
    for (int ks = 0; ks < 5; ++ks) {
      int boff = bcol * 160 + ks * 32 + fq * 8;
      short8v bh = *reinterpret_cast<const short8v*>(W2H + boff);
      short8v bl = *reinterpret_cast<const short8v*>(W2L + boff);
      int a0 = (0 * 16 + fr) * 168 + ks * 32 + fq * 8;
      int a1 = (1 * 16 + fr) * 168 + ks * 32 + fq * 8;
      int a2 = (2 * 16 + fr) * 168 + ks * 32 + fq * 8;
      short8v ah0 = *reinterpret_cast<const short8v*>(ahi + a0);
      short8v al0 = *reinterpret_cast<const short8v*>(alo + a0);
      MF3(c0, ah0, al0, bh, bl);
      short8v ah1 = *reinterpret_cast<const short8v*>(ahi + a1);
      short8v al1 = *reinterpret_cast<const short8v*>(alo + a1);
      MF3(c1, ah1, al1, bh, bl);
      short8v ah2 = *reinterpret_cast<const short8v*>(ahi + a2);
      short8v al2 = *reinterpret_cast<const short8v*>(alo + a2);
      MF3(c2, ah2, al2, bh, bl);
    }
    float bias = b2[bcol];
    #pragma unroll
    for (int j = 0; j < 4; ++j) {
      int r0 = fq * 4 + j;
      hout[(pbase + r0) * 80 + bcol] = o0[j] + c0[j] + bias;
      int r1 = 16 + r0;
      hout[(pbase + r1) * 80 + bcol] = o1[j] + c1[j] + bias;
      int r2 = 32 + r0;
      if (r2 < 40) hout[(pbase + r2) * 80 + bcol] = o2[j] + c2[j] + bias;
    }
  }
}

// ---------------- Readout MLP 80->40->20->64->{3,1} (f32 vector) ----------------
__global__ __launch_bounds__(320) void readout_kernel(const float* __restrict__ h, const float* __restrict__ Wr0,
                                                      const float* __restrict__ br0, const float* __restrict__ Wr1,
                                                      const float* __restrict__ br1, const float* __restrict__ Wr2,
                                                      const float* __restrict__ br2, const float* __restrict__ Wc,
                                                      const float* __restrict__ Wb, const float* __restrict__ bb,
                                                      float* __restrict__ out) {
  __shared__ __align__(16) float hs[3200];
  __shared__ __align__(16) float y0s[40 * 40];
  __shared__ __align__(16) float y1s[40 * 20];
  __shared__ __align__(16) float y2s[40 * 64];
  size_t p0 = (size_t)blockIdx.x * 40;
  int tid = threadIdx.x;
  {
    const float4* src = reinterpret_cast<const float4*>(h + p0 * 80);
    float4* dst = reinterpret_cast<float4*>(hs);
    for (int i = tid; i < 800; i += 320) dst[i] = src[i];
  }
  __syncthreads();
  {  // y0 = relu(h@Wr0 + br0)
    int c = tid % 40, grp = tid / 40;  // 0..7
    if (grp < 5) {
      float wcol[80];
      #pragma unroll
      for (int kk = 0; kk < 80; ++kk) wcol[kk] = Wr0[kk * 40 + c];
      float bias = br0[c];
      float acc[8] = {};
      #pragma unroll
      for (int j = 0; j < 8; ++j) {
        const float4* r4 = reinterpret_cast<const float4*>(hs + (grp * 8 + j) * 80);
        #pragma unroll
        for (int kq = 0; kq < 20; ++kq) {
          float4 hv = r4[kq];
          acc[j] = fmaf(hv.x, wcol[4 * kq + 0], acc[j]);
          acc[j] = fmaf(hv.y, wcol[4 * kq + 1], acc[j]);
          acc[j] = fmaf(hv.z, wcol[4 * kq + 2], acc[j]);
          acc[j] = fmaf(hv.w, wcol[4 * kq + 3], acc[j]);
        }
      }
      #pragma unroll
      for (int j = 0; j < 8; ++j) y0s[(grp * 8 + j) * 40 + c] = fmaxf(acc[j] + bias, 0.f);
    }
  }
  __syncthreads();
  {  // y1 = relu(y0@Wr1 + br1)
    int c = tid % 20, grp = tid / 20;  // 0..15
    if (grp < 5) {
      float wcol[40];
      #pragma unroll
      for (int kk = 0; kk < 40; ++kk) wcol[kk] = Wr1[kk * 20 + c];
      float bias = br1[c];
      float acc[8] = {};
      #pragma unroll
      for (int j = 0; j < 8; ++j) {
        const float4* r4 = reinterpret_cast<const float4*>(y0s + (grp * 8 + j) * 40);
        #pragma unroll
        for (int kq = 0; kq < 10; ++kq) {
          float4 hv = r4[kq];
          acc[j] = fmaf(hv.x, wcol[4 * kq + 0], acc[j]);
          acc[j] = fmaf(hv.y, wcol[4 * kq + 1], acc[j]);
          acc[j] = fmaf(hv.z, wcol[4 * kq + 2], acc[j]);
          acc[j] = fmaf(hv.w, wcol[4 * kq + 3], acc[j]);
        }
      }
      #pragma unroll
      for (int j = 0; j < 8; ++j) y1s[(grp * 8 + j) * 20 + c] = fmaxf(acc[j] + bias, 0.f);
    }
  }
  __syncthreads();
  {  // y2 = y1@Wr2 + br2
    int c = tid % 64, grp = tid / 64;  // 0..4
    float wcol[20];
    #pragma unroll
    for (int kk = 0; kk < 20; ++kk) wcol[kk] = Wr2[kk * 64 + c];
    float bias = br2[c];
    float acc[8] = {};
    #pragma unroll
    for (int j = 0; j < 8; ++j) {
      const float4* r4 = reinterpret_cast<const float4*>(y1s + (grp * 8 + j) * 20);
      #pragma unroll
      for (int kq = 0; kq < 5; ++kq) {
        float4 hv = r4[kq];
        acc[j] = fmaf(hv.x, wcol[4 * kq + 0], acc[j]);
        acc[j] = fmaf(hv.y, wcol[4 * kq + 1], acc[j]);
        acc[j] = fmaf(hv.z, wcol[4 * kq + 2], acc[j]);
        acc[j] = fmaf(hv.w, wcol[4 * kq + 3], acc[j]);
      }
    }
    #pragma unroll
    for (int j = 0; j < 8; ++j) y2s[(grp * 8 + j) * 64 + c] = acc[j] + bias;
  }
  __syncthreads();
  {  // out: cc = y2@Wc, beta = y2@Wb + bb
    int c = tid % 4, p = tid / 4;
    if (p < 40) {
      float wcol[64];
      if (c < 3) {
        #pragma unroll
        for (int kk = 0; kk < 64; ++kk) wcol[kk] = Wc[kk * 3 + c];
      } else {
        #pragma unroll
        for (int kk = 0; kk < 64; ++kk) wcol[kk] = Wb[kk];
      }
      float acc = 0.f;
      #pragma unroll
      for (int kk = 0; kk < 64; ++kk) acc = fmaf(y2s[p * 64 + kk], wcol[kk], acc);
      if (c == 3) acc += bb[0];
      out[(p0 + p) * 4 + c] = acc;
    }
  }
}

extern "C" void kernel_launch(void* const* d_in, const int* in_sizes, int n_in,
                              void* d_out, int out_size, void* d_ws, size_t ws_size,
                              hipStream_t stream) {
  const float* hf = (const float*)d_in[0];
  const float* gamma = (const float*)d_in[1];
  const float* beta = (const float*)d_in[2];
  const float* We = (const float*)d_in[3];
  const float* be = (const float*)d_in[4];
  const float* Wq = (const float*)d_in[5];
  const float* Wk = (const float*)d_in[6];
  const float* Wv = (const float*)d_in[7];
  const float* Wo = (const float*)d_in[8];
  const float* bo = (const float*)d_in[9];
  const float* W1 = (const float*)d_in[10];
  const float* b1 = (const float*)d_in[11];
  const float* W2 = (const float*)d_in[12];
  const float* b2 = (const float*)d_in[13];
  const float* Wr0 = (const float*)d_in[14];
  const float* br0 = (const float*)d_in[15];
  const float* Wr1 = (const float*)d_in[16];
  const float* br1 = (const float*)d_in[17];
  const float* Wr2 = (const float*)d_in[18];
  const float* br2 = (const float*)d_in[19];
  const float* Wc = (const float*)d_in[20];
  const float* Wb = (const float*)d_in[21];
  const float* bb = (const float*)d_in[22];
  float* out = (float*)d_out;

  // Workspace: 3 big f32 buffers + nbr + weights ~= 256.4 MB (r7-proven budget; r8's 4th buffer overflowed)
  char* wsp = (char*)d_ws;
  int* nbr = (int*)wsp;            wsp += (size_t)256000 * 8 * 4;
  float* hA = (float*)wsp;         wsp += (size_t)256000 * 80 * 4;
  float* kbuf = (float*)wsp;       wsp += (size_t)256000 * 80 * 4;
  float* vbuf = (float*)wsp;       wsp += (size_t)256000 * 80 * 4;
  float* partial = (float*)wsp;    wsp += (size_t)1000 * 18 * 4;
  float* stats = (float*)wsp;      wsp += 128;
  unsigned short* WqH = (unsigned short*)wsp; wsp += (size_t)10 * 7680 * 2;
  unsigned short* WqL = (unsigned short*)wsp; wsp += (size_t)10 * 7680 * 2;
  unsigned short* WkH = (unsigned short*)wsp; wsp += (size_t)10 * 7680 * 2;
  unsigned short* WkL = (unsigned short*)wsp; wsp += (size_t)10 * 7680 * 2;
  unsigned short* WvH = (unsigned short*)wsp; wsp += (size_t)10 * 7680 * 2;
  unsigned short* WvL = (unsigned short*)wsp; wsp += (size_t)10 * 7680 * 2;
  unsigned short* WoH = (unsigned short*)wsp; wsp += (size_t)10 * 7680 * 2;
  unsigned short* WoL = (unsigned short*)wsp; wsp += (size_t)10 * 7680 * 2;
  unsigned short* W1H = (unsigned short*)wsp; wsp += (size_t)10 * 15360 * 2;
  unsigned short* W1L = (unsigned short*)wsp; wsp += (size_t)10 * 15360 * 2;
  unsigned short* W2H = (unsigned short*)wsp; wsp += (size_t)10 * 12800 * 2;
  unsigned short* W2L = (unsigned short*)wsp; wsp += (size_t)10 * 12800 * 2;

  knn_kernel<<<1024, 256, 0, stream>>>(hf, nbr);
  bn_stat1<<<1000, 256, 0, stream>>>(hf, partial);
  bn_stat2<<<1, 256, 0, stream>>>(partial, stats);
  split_tr<<<10, 256, 0, stream>>>(Wq, WqH, WqL, 80, 80, 96);
  split_tr<<<10, 256, 0, stream>>>(Wk, WkH, WkL, 80, 80, 96);
  split_tr<<<10, 256, 0, stream>>>(Wv, WvH, WvL, 80, 80, 96);
  split_tr<<<10, 256, 0, stream>>>(Wo, WoH, WoL, 80, 80, 96);
  split_tr<<<10, 256, 0, stream>>>(W1, W1H, W1L, 80, 160, 96);
  split_tr<<<10, 256, 0, stream>>>(W2, W2H, W2L, 160, 80, 160);
  embed_kernel<<<6400, 320, 0, stream>>>(hf, stats, gamma, beta, We, be, hA);
  for (int l = 0; l < 10; ++l) {
    kv_kernel<<<6400, 320, 0, stream>>>(hA, WkH + (size_t)l * 7680, WkL + (size_t)l * 7680,
                                        WvH + (size_t)l * 7680, WvL + (size_t)l * 7680, kbuf, vbuf);
    battn_kernel<<<6400, 320, 0, stream>>>(hA, kbuf, vbuf, nbr,
                                           WqH + (size_t)l * 7680, WqL + (size_t)l * 7680,
                                           WoH + (size_t)l * 7680, WoL + (size_t)l * 7680, bo + (size_t)l * 80,
                                           W1H + (size_t)l * 15360, W1L + (size_t)l * 15360, b1 + (size_t)l * 160,
                                           W2H + (size_t)l * 12800, W2L + (size_t)l * 12800, b2 + (size_t)l * 80, hA);
  }
  readout_kernel<<<6400, 320, 0, stream>>>(hA, Wr0, br0, Wr1, br1, Wr2, br2, Wc, Wb, bb, out);
}